// Round 13
// baseline (442.125 us; speedup 1.0000x reference)
//
#include <hip/hip_runtime.h>
#include <math.h>

typedef float f2 __attribute__((ext_vector_type(2)));
typedef float f2u __attribute__((ext_vector_type(2), aligned(4)));
typedef float f4 __attribute__((ext_vector_type(4)));

#define BN 8
#define CIN 3
#define HH 512
#define WW 512
#define KK 9
#define PATCH 27

// ws layout (floats) — identical to R10:
//  A [0,756): conv weights: elem i (0..26), 28 floats each: r=2q+half ->
//             q<13: w_off[(2q+half)*27+i]; q==13: half? 0 : w_off[26*27+i]
//  B [756,900): per-tap k, 16 floats: r<12: c=r>>2,o=r&3 -> o<3 ? w_def[o*27+c*9+k] : 0
//  C [900,928): ow-init pairs: r=2q+half -> q<13: b_off[2q+half]; q==13: half? 0 : b_off[26]
__global__ void reorder_weights(const float* __restrict__ w_off,
                                const float* __restrict__ b_off,
                                const float* __restrict__ w_def,
                                float* __restrict__ ws)
{
    for (int idx = threadIdx.x; idx < 928; idx += blockDim.x) {
        float v = 0.0f;
        if (idx < 756) {
            const int i = idx / 28, r = idx % 28;
            const int q = r >> 1, half = r & 1;
            if (q < 13)      v = w_off[(2 * q + half) * PATCH + i];
            else if (!half)  v = w_off[26 * PATCH + i];
        } else if (idx < 900) {
            const int t = idx - 756;
            const int k = t / 16, r = t % 16;
            if (r < 12) {
                const int c = r >> 2, o = r & 3;
                if (o < 3) v = w_def[o * PATCH + c * KK + k];
            }
        } else {
            const int r = idx - 900;
            const int q = r >> 1, half = r & 1;
            if (q < 13)      v = b_off[2 * q + half];
            else if (!half)  v = b_off[26];
        }
        ws[idx] = v;
    }
}

template <int K>
__device__ __forceinline__ void tap(
    const float* __restrict__ xb, const size_t plane,
    const int h, const int w,
    const float* __restrict__ blk,   // wsw + 756 + K*16 (uniform -> s_load)
    const float oy, const float ox, const float om,
    f2& acc01, float& acc2)
{
    const float m = __builtin_amdgcn_rcpf(1.0f + __expf(-om));

    const float py = (float)h + (float)(K / 3 - 1) + oy;
    const float px = (float)w + (float)(K % 3 - 1) + ox;
    const float y0f = floorf(py);
    const float x0f = floorf(px);
    const float dy = py - y0f;
    const float dx = px - x0f;
    const int y0 = (int)y0f;
    const int x0 = (int)x0f;

    const f2 dxp = { 1.0f - dx, dx };
    const f2 wTe = dxp * ((1.0f - dy) * m);   // (w00, w01) * m
    const f2 wBe = dxp * (dy * m);            // (w10, w11) * m

    const int interior = ((unsigned)y0 < (HH - 1)) & ((unsigned)x0 < (WW - 1));

    if (__all(interior)) {
        const int idx = y0 * WW + x0;
        #pragma unroll
        for (int c = 0; c < CIN; ++c) {
            const float* xp = xb + c * plane + idx;
            const f2 vT = *(const f2u*)(xp);
            const f2 vB = *(const f2u*)(xp + WW);
            f2 s = vT * wTe;
            s = __builtin_elementwise_fma(vB, wBe, s);
            const float val = s.x + s.y;
            const f4 wq = *(const f4*)(blk + 4 * c);   // (wd0, wd1, wd2, 0)
            const f2 w01 = { wq.x, wq.y };
            const f2 vv = { val, val };
            acc01 = __builtin_elementwise_fma(w01, vv, acc01);
            acc2 = fmaf(wq.z, val, acc2);
        }
    } else {
        const bool vy0 = (unsigned)y0 < HH;
        const bool vy1 = (unsigned)(y0 + 1) < HH;
        const bool vx0 = (unsigned)x0 < WW;
        const bool vx1 = (unsigned)(x0 + 1) < WW;

        const int yc0 = min(max(y0, 0), HH - 1);
        const int yc1 = min(max(y0 + 1, 0), HH - 1);
        const int xc0 = min(max(x0, 0), WW - 1);
        const int xc1 = min(max(x0 + 1, 0), WW - 1);

        #pragma unroll
        for (int c = 0; c < CIN; ++c) {
            const float* xp = xb + c * plane;
            const float v00 = (vy0 & vx0) ? xp[yc0 * WW + xc0] : 0.0f;
            const float v01 = (vy0 & vx1) ? xp[yc0 * WW + xc1] : 0.0f;
            const float v10 = (vy1 & vx0) ? xp[yc1 * WW + xc0] : 0.0f;
            const float v11 = (vy1 & vx1) ? xp[yc1 * WW + xc1] : 0.0f;

            const float val =
                v00 * wTe.x + v01 * wTe.y + v10 * wBe.x + v11 * wBe.y;
            const f4 wq = *(const f4*)(blk + 4 * c);
            const f2 w01 = { wq.x, wq.y };
            const f2 vv = { val, val };
            acc01 = __builtin_elementwise_fma(w01, vv, acc01);
            acc2 = fmaf(wq.z, val, acc2);
        }
    }
}

__global__ __launch_bounds__(256) void deform_fused_kernel(
    const float* __restrict__ x,
    const float* __restrict__ wsw,    // reordered weights, 928 floats (uniform -> SMEM)
    const float* __restrict__ b_def,
    float* __restrict__ out)
{
    const int w = blockIdx.x * blockDim.x + threadIdx.x;
    const int h = blockIdx.y;
    const int b = blockIdx.z;

    const size_t plane = (size_t)HH * WW;
    const float* xb = x + (size_t)b * CIN * plane;

    // ---- 3x3x3 zero-padded patch, flat index = c*9 + t ----
    float patch[PATCH];
    const bool pint = (h >= 1) & (h < HH - 1) & (w >= 1) & (w < WW - 1);
    if (__all(pint)) {
        const float* pc = xb + h * WW + w;
        #pragma unroll
        for (int c = 0; c < CIN; ++c) {
            const float* xp = pc + c * plane;
            #pragma unroll
            for (int d = 0; d < 3; ++d)
                #pragma unroll
                for (int e = 0; e < 3; ++e)
                    patch[c * KK + d * 3 + e] = xp[(d - 1) * WW + (e - 1)];
        }
    } else {
        #pragma unroll
        for (int c = 0; c < CIN; ++c) {
            const float* xp = xb + c * plane;
            #pragma unroll
            for (int t = 0; t < KK; ++t) {
                const int yy = h + t / 3 - 1;
                const int xx = w + t % 3 - 1;
                const bool in = ((unsigned)yy < HH) & ((unsigned)xx < WW);
                const int yc = min(max(yy, 0), HH - 1);
                const int xc = min(max(xx, 0), WW - 1);
                patch[c * KK + t] = in ? xp[yc * WW + xc] : 0.0f;
            }
        }
    }

    // ---- hoisted offset conv: 27 channels as 14 packed pairs (pair13.y dummy) ----
    f2 ow[14];
    #pragma unroll
    for (int q = 0; q < 14; ++q) ow[q] = *(const f2*)(wsw + 900 + 2 * q);

    #pragma unroll
    for (int i = 0; i < PATCH; ++i) {
        const float p = patch[i];
        const f2 pp = { p, p };
        const f4* row = (const f4*)(wsw + i * 28);
        #pragma unroll
        for (int j = 0; j < 7; ++j) {
            const f4 wq = row[j];
            const f2 lo = { wq.x, wq.y };
            const f2 hi = { wq.z, wq.w };
            ow[2 * j]     = __builtin_elementwise_fma(lo, pp, ow[2 * j]);
            ow[2 * j + 1] = __builtin_elementwise_fma(hi, pp, ow[2 * j + 1]);
        }
    }

    f2 acc01 = { b_def[0], b_def[1] };
    float acc2 = b_def[2];

    // ---- 9 taps, explicit constexpr instantiation (ow[] indices all constant) ----
    const float* wb = wsw + 756;
    tap<0>(xb, plane, h, w, wb + 0 * 16, ow[0].x, ow[0].y, ow[9].x,  acc01, acc2);
    tap<1>(xb, plane, h, w, wb + 1 * 16, ow[1].x, ow[1].y, ow[9].y,  acc01, acc2);
    tap<2>(xb, plane, h, w, wb + 2 * 16, ow[2].x, ow[2].y, ow[10].x, acc01, acc2);
    tap<3>(xb, plane, h, w, wb + 3 * 16, ow[3].x, ow[3].y, ow[10].y, acc01, acc2);
    tap<4>(xb, plane, h, w, wb + 4 * 16, ow[4].x, ow[4].y, ow[11].x, acc01, acc2);
    tap<5>(xb, plane, h, w, wb + 5 * 16, ow[5].x, ow[5].y, ow[11].y, acc01, acc2);
    tap<6>(xb, plane, h, w, wb + 6 * 16, ow[6].x, ow[6].y, ow[12].x, acc01, acc2);
    tap<7>(xb, plane, h, w, wb + 7 * 16, ow[7].x, ow[7].y, ow[12].y, acc01, acc2);
    tap<8>(xb, plane, h, w, wb + 8 * 16, ow[8].x, ow[8].y, ow[13].x, acc01, acc2);

    const size_t base = (size_t)b * (CIN * plane) + (size_t)h * WW + w;
    out[base]             = acc01.x;
    out[base + plane]     = acc01.y;
    out[base + 2 * plane] = acc2;
}

extern "C" void kernel_launch(void* const* d_in, const int* in_sizes, int n_in,
                              void* d_out, int out_size, void* d_ws, size_t ws_size,
                              hipStream_t stream) {
    const float* x     = (const float*)d_in[0];
    const float* w_off = (const float*)d_in[1];
    const float* b_off = (const float*)d_in[2];
    const float* w_def = (const float*)d_in[3];
    const float* b_def = (const float*)d_in[4];
    float* out = (float*)d_out;
    float* wsw = (float*)d_ws;   // 928 floats of reordered weights

    reorder_weights<<<1, 256, 0, stream>>>(w_off, b_off, w_def, wsw);

    dim3 block(256, 1, 1);
    dim3 grid(WW / 256, HH, BN);  // (2, 512, 8)
    deform_fused_kernel<<<grid, block, 0, stream>>>(x, wsw, b_def, out);
}